// Round 11
// baseline (1991.543 us; speedup 1.0000x reference)
//
#include <hip/hip_runtime.h>
#include <math.h>

#define Bb 8
#define Nn 2048
#define Mm 2048
#define Dd 256
#define TOPK 128
#define SK_ITERS 20
#define RB 8              // rows per barrier batch in fused kernel
#define NEG_INIT (-1e30f)
// -1/(eps*ln2): cost -> log2-domain scaled score
#define SCALE_L2 (-1442.6950408889634f)

// ---- branchless log2-domain LSE merge: (m,s) <- merge((m,s),(m2,s2)) ----
__device__ __forceinline__ void lse_merge(float& m, float& s, float m2, float s2) {
    float d = m2 - m;
    float e = exp2f(-fabsf(d));
    bool up = (d > 0.f);
    s = up ? fmaf(s, e, s2) : fmaf(s2, e, s);
    m = up ? m2 : m;
}

// ---------------- init: marginals -> log2 p / log2 q, Ve = 0 ----------------
__global__ void wl_init_kernel(const float* __restrict__ src_o, const float* __restrict__ tgt_o,
                               float* __restrict__ logp2, float* __restrict__ logq2,
                               float* __restrict__ Ve) {
    __shared__ float lds[8];
    int b = blockIdx.x, t = threadIdx.x;
    int l = t & 63, w = t >> 6;
    float s = 0.f, q = 0.f;
    for (int i = t; i < Nn; i += 256) s += src_o[b * Nn + i];
    for (int i = t; i < Mm; i += 256) q += tgt_o[b * Mm + i];
    for (int o = 32; o; o >>= 1) { s += __shfl_xor(s, o); q += __shfl_xor(q, o); }
    if (l == 0) { lds[w] = s; lds[4 + w] = q; }
    __syncthreads();
    float ssum = fmaxf(lds[0] + lds[1] + lds[2] + lds[3], 1e-4f);
    float qsum = fmaxf(lds[4] + lds[5] + lds[6] + lds[7], 1e-4f);
    float rs = 1.f / ssum, rq = 1.f / qsum;
    for (int i = t; i < Nn; i += 256) logp2[b * Nn + i] = log2f(src_o[b * Nn + i] * rs);
    for (int i = t; i < Mm; i += 256) { logq2[b * Mm + i] = log2f(tgt_o[b * Mm + i] * rq); Ve[b * Mm + i] = 0.f; }
}

// ---------------- squared row norms ----------------
__global__ void wl_norms_kernel(const float* __restrict__ feats, float* __restrict__ out) {
    int w = threadIdx.x >> 6, l = threadIdx.x & 63;
    int row = blockIdx.x * 4 + w;             // [0, B*2048)
    float4 f = ((const float4*)(feats + (size_t)row * Dd))[l];
    float s = f.x * f.x + f.y * f.y + f.z * f.z + f.w * f.w;
    for (int o = 32; o; o >>= 1) s += __shfl_xor(s, o);
    if (l == 0) out[row] = s;
}

// ---------------- cost GEMM: Sc = -||fx - fy|| / (eps*ln2) ----------------
#define BT 128
#define KT 32
#define LDT 132
__global__ __launch_bounds__(256)
void wl_cost_kernel(const float* __restrict__ A, const float* __restrict__ Bf,
                    const float* __restrict__ nx, const float* __restrict__ ny,
                    float* __restrict__ Sc) {
    __shared__ float As[KT][LDT];
    __shared__ float Bs[KT][LDT];
    int b = blockIdx.z;
    int n0 = blockIdx.y * BT, m0 = blockIdx.x * BT;
    const float* Ab = A + (size_t)b * Nn * Dd;
    const float* Bbp = Bf + (size_t)b * Mm * Dd;
    int t = threadIdx.x;
    int w = t >> 6, l = t & 63;
    int tx = (w & 1) * 8 + (l & 7);   // 0..15 col group
    int ty = (w >> 1) * 8 + (l >> 3); // 0..15 row group
    float acc[8][8] = {};
    for (int k0 = 0; k0 < Dd; k0 += KT) {
        __syncthreads();
#pragma unroll
        for (int i = 0; i < 4; i++) {
            int c = t + 256 * i;          // 0..1023
            int row = c >> 3, kc = (c & 7) << 2;
            float4 v = *(const float4*)(Ab + (size_t)(n0 + row) * Dd + k0 + kc);
            As[kc + 0][row] = v.x; As[kc + 1][row] = v.y; As[kc + 2][row] = v.z; As[kc + 3][row] = v.w;
            float4 u = *(const float4*)(Bbp + (size_t)(m0 + row) * Dd + k0 + kc);
            Bs[kc + 0][row] = u.x; Bs[kc + 1][row] = u.y; Bs[kc + 2][row] = u.z; Bs[kc + 3][row] = u.w;
        }
        __syncthreads();
#pragma unroll 4
        for (int k = 0; k < KT; k++) {
            float4 a0 = *(const float4*)&As[k][ty * 8];
            float4 a1 = *(const float4*)&As[k][ty * 8 + 4];
            float4 b0 = *(const float4*)&Bs[k][tx * 8];
            float4 b1 = *(const float4*)&Bs[k][tx * 8 + 4];
            float a[8] = { a0.x, a0.y, a0.z, a0.w, a1.x, a1.y, a1.z, a1.w };
            float bv[8] = { b0.x, b0.y, b0.z, b0.w, b1.x, b1.y, b1.z, b1.w };
#pragma unroll
            for (int i = 0; i < 8; i++)
#pragma unroll
                for (int j = 0; j < 8; j++)
                    acc[i][j] = fmaf(a[i], bv[j], acc[i][j]);
        }
    }
    float nyv[8];
#pragma unroll
    for (int j = 0; j < 8; j++) nyv[j] = ny[b * Mm + m0 + tx * 8 + j];
#pragma unroll
    for (int i = 0; i < 8; i++) {
        int n = n0 + ty * 8 + i;
        float nxv = nx[b * Nn + n];
        float o[8];
#pragma unroll
        for (int j = 0; j < 8; j++) {
            float d2 = nxv + nyv[j] - 2.f * acc[i][j];
            d2 = fmaxf(d2, 0.f);
            float c = d2 > 0.f ? sqrtf(d2) : 0.f;
            o[j] = SCALE_L2 * c;
        }
        float* orow = Sc + ((size_t)b * Nn + n) * Mm + m0 + tx * 8;
        *(float4*)orow = make_float4(o[0], o[1], o[2], o[3]);
        *(float4*)(orow + 4) = make_float4(o[4], o[5], o[6], o[7]);
    }
}

// ---------------- fused sinkhorn pass: 2-deep pipelined batches (T14) ----------------
// Same algebra as the (passing) round-7 kernel; only scheduling changed:
// while batch i is reduced/merged (shuffles + 1 barrier), batch i+1's global
// loads are already in flight in a second register buffer. Statically named
// tva/tvb (rule #20: no runtime-indexed reg arrays).
__device__ __forceinline__ void wl_load_batch(float4 (&tv)[RB], const float* scb,
                                              int batch, int nbatch, float4 ve) {
    int rr = batch < nbatch ? batch : nbatch - 1;   // clamp (tail prefetch harmless)
    const float* p = scb + (size_t)rr * RB * Mm;
#pragma unroll
    for (int r = 0; r < RB; r++) {
        float4 sv = *(const float4*)(p + (size_t)r * Mm);
        tv[r].x = sv.x + ve.x; tv[r].y = sv.y + ve.y;
        tv[r].z = sv.z + ve.z; tv[r].w = sv.w + ve.w;
    }
}

__device__ __forceinline__ void wl_proc_batch(float4 (&tv)[RB], int par, int rbase,
        float (&prm)[2][RB][8], float (&prs)[2][RB][8],
        const float* lpb, float* ueb, int t, int w, int l,
        float& cm0, float& cs0, float& cm1, float& cs1,
        float& cm2, float& cs2, float& cm3, float& cs3) {
#pragma unroll
    for (int r = 0; r < RB; r++) {
        float m = fmaxf(fmaxf(tv[r].x, tv[r].y), fmaxf(tv[r].z, tv[r].w));
        for (int o = 32; o; o >>= 1) m = fmaxf(m, __shfl_xor(m, o));
        float s = exp2f(tv[r].x - m) + exp2f(tv[r].y - m)
                + exp2f(tv[r].z - m) + exp2f(tv[r].w - m);
        for (int o = 32; o; o >>= 1) s += __shfl_xor(s, o);
        if (l == 0) { prm[par][r][w] = m; prs[par][r][w] = s; }
    }
    __syncthreads();
#pragma unroll
    for (int r = 0; r < RB; r++) {
        float M = prm[par][r][0];
#pragma unroll
        for (int ww = 1; ww < 8; ww++) M = fmaxf(M, prm[par][r][ww]);
        float S = 0.f;
#pragma unroll
        for (int ww = 0; ww < 8; ww++) S = fmaf(prs[par][r][ww], exp2f(prm[par][r][ww] - M), S);
        float C = lpb[rbase + r] - log2f(S) - M;   // == Ue[row]
        if (t == 0) ueb[rbase + r] = C;
        lse_merge(cm0, cs0, tv[r].x + C, 1.f);
        lse_merge(cm1, cs1, tv[r].y + C, 1.f);
        lse_merge(cm2, cs2, tv[r].z + C, 1.f);
        lse_merge(cm3, cs3, tv[r].w + C, 1.f);
    }
}

__global__ __launch_bounds__(512)
void wl_fused_kernel(const float* __restrict__ Sc, const float* __restrict__ Ve,
                     const float* __restrict__ logp2, float* __restrict__ Ue,
                     float* __restrict__ pmx, float* __restrict__ psm, int nch) {
    __shared__ float prm[2][RB][8];
    __shared__ float prs[2][RB][8];
    int b = blockIdx.y, ch = blockIdx.x;
    int t = threadIdx.x, w = t >> 6, l = t & 63;
    int chrows = Nn / nch;            // 32 (nch=64) or 64 (nch=32); /RB is even
    int row0 = ch * chrows;
    int colbase = (w << 8) | (l << 2);

    float4 ve = *(const float4*)(Ve + b * Mm + colbase);
    float cm0 = NEG_INIT, cm1 = NEG_INIT, cm2 = NEG_INIT, cm3 = NEG_INIT;
    float cs0 = 0.f, cs1 = 0.f, cs2 = 0.f, cs3 = 0.f;

    const float* scb = Sc + ((size_t)b * Nn + row0) * Mm + colbase;
    const float* lpb = logp2 + b * Nn + row0;
    float* ueb = Ue + b * Nn + row0;

    int nbatch = chrows / RB;         // 4 or 8 (even)
    float4 tva[RB], tvb[RB];
    wl_load_batch(tva, scb, 0, nbatch, ve);
    for (int i = 0; i < nbatch; i += 2) {
        wl_load_batch(tvb, scb, i + 1, nbatch, ve);          // prefetch odd batch
        wl_proc_batch(tva, 0, i * RB, prm, prs, lpb, ueb, t, w, l,
                      cm0, cs0, cm1, cs1, cm2, cs2, cm3, cs3);
        wl_load_batch(tva, scb, i + 2, nbatch, ve);          // prefetch next even batch
        wl_proc_batch(tvb, 1, (i + 1) * RB, prm, prs, lpb, ueb, t, w, l,
                      cm0, cs0, cm1, cs1, cm2, cs2, cm3, cs3);
    }

    size_t gi = ((size_t)(b * nch + ch)) * Mm + colbase;
    *(float4*)(pmx + gi) = make_float4(cm0, cm1, cm2, cm3);
    *(float4*)(psm + gi) = make_float4(cs0, cs1, cs2, cs3);
}

// ---------------- v-combine: Ve' = logq2 + Ve_old - LSE_x ----------------
// 256 blocks; block owns 64 cols, 4 threads/col each merging nch/4 chunks,
// then a 2 KB LDS merge. 4x the parallelism of the old 64-block version.
__global__ __launch_bounds__(256)
void wl_v_combine_kernel(const float* __restrict__ pmx, const float* __restrict__ psm,
                         const float* __restrict__ logq2, float* __restrict__ Ve, int nch) {
    __shared__ float lm[4][64], ls[4][64];
    int t = threadIdx.x;
    int quarter = t >> 6, cidx = t & 63;
    int col = blockIdx.x * 64 + cidx;         // [0, Bb*Mm)
    int b = col >> 11, m = col & (Mm - 1);
    int cpq = nch >> 2;
    const float* pbm = pmx + ((size_t)(b * nch + quarter * cpq)) * Mm + m;
    const float* pbs = psm + ((size_t)(b * nch + quarter * cpq)) * Mm + m;
    float mx = NEG_INIT, sm = 0.f;
    for (int ch = 0; ch < cpq; ch++)
        lse_merge(mx, sm, pbm[(size_t)ch * Mm], pbs[(size_t)ch * Mm]);
    lm[quarter][cidx] = mx; ls[quarter][cidx] = sm;
    __syncthreads();
    if (quarter == 0) {
#pragma unroll
        for (int qq = 1; qq < 4; qq++) lse_merge(mx, sm, lm[qq][cidx], ls[qq][cidx]);
        Ve[col] = logq2[col] + Ve[col] - mx - log2f(sm);
    }
}

// ---------------- finalize: prob = max gamma, corr = (gamma@tgt)/clip(rowsum) ----------------
__global__ __launch_bounds__(256)
void wl_finalize_kernel(const float* __restrict__ Sc, const float* __restrict__ Ue,
                        const float* __restrict__ Ve, const float* __restrict__ tgt,
                        float* __restrict__ prob, float* __restrict__ corr) {
    int w = threadIdx.x >> 6, l = threadIdx.x & 63;
    int row = blockIdx.x * 4 + w;
    int b = row >> 11;
    const float4* s4 = (const float4*)(Sc + (size_t)row * Mm);
    const float4* v4 = (const float4*)(Ve + (size_t)b * Mm);
    const float4* tg4 = (const float4*)(tgt + (size_t)b * Mm * 3);
    float mx = NEG_INIT, sm = 0.f, w0 = 0.f, w1 = 0.f, w2 = 0.f;
#pragma unroll
    for (int i = 0; i < 8; i++) {
        int c = l + 64 * i;
        float4 sv = s4[c]; float4 vv = v4[c];
        float4 g0 = tg4[3 * c + 0], g1 = tg4[3 * c + 1], g2 = tg4[3 * c + 2];
        float tt[4] = { sv.x + vv.x, sv.y + vv.y, sv.z + vv.z, sv.w + vv.w };
        float gx[4] = { g0.x, g0.w, g1.z, g2.y };
        float gy[4] = { g0.y, g1.x, g1.w, g2.z };
        float gz[4] = { g0.z, g1.y, g2.x, g2.w };
#pragma unroll
        for (int j = 0; j < 4; j++) {
            float nm = fmaxf(mx, tt[j]);
            float ce = exp2f(mx - nm), e = exp2f(tt[j] - nm);
            sm = sm * ce + e;
            w0 = w0 * ce + e * gx[j];
            w1 = w1 * ce + e * gy[j];
            w2 = w2 * ce + e * gz[j];
            mx = nm;
        }
    }
    for (int o = 32; o; o >>= 1) {
        float om = __shfl_xor(mx, o), os = __shfl_xor(sm, o);
        float o0 = __shfl_xor(w0, o), o1 = __shfl_xor(w1, o), o2 = __shfl_xor(w2, o);
        float nm = fmaxf(mx, om);
        float c1 = exp2f(mx - nm), c2 = exp2f(om - nm);
        sm = sm * c1 + os * c2;
        w0 = w0 * c1 + o0 * c2;
        w1 = w1 * c1 + o1 * c2;
        w2 = w2 * c1 + o2 * c2;
        mx = nm;
    }
    if (l == 0) {
        float scale = exp2f(Ue[row] + mx);   // = max_m gamma
        float rowsum = scale * sm;
        float den = fmaxf(rowsum, 1e-4f);
        prob[row] = scale;
        corr[(size_t)row * 3 + 0] = scale * w0 / den;
        corr[(size_t)row * 3 + 1] = scale * w1 / den;
        corr[(size_t)row * 3 + 2] = scale * w2 / den;
    }
}

// ---------------- top-k via bitonic sort (1024 threads: 1 compare/thread) ----------------
__global__ __launch_bounds__(1024)
void wl_topk_kernel(const float* __restrict__ prob, int* __restrict__ topk) {
    __shared__ float key[2048];
    __shared__ int val[2048];
    int b = blockIdx.x, t = threadIdx.x;
    for (int i = t; i < 2048; i += 1024) { key[i] = prob[b * 2048 + i]; val[i] = i; }
    __syncthreads();
    for (int size = 2; size <= 2048; size <<= 1) {
        for (int stride = size >> 1; stride > 0; stride >>= 1) {
            int q = t;   // 1024 compare-exchange pairs, one per thread
            int i = 2 * q - (q & (stride - 1));
            int j = i + stride;
            bool up = ((i & size) == 0);
            float ki = key[i], kj = key[j];
            int vi = val[i], vj = val[j];
            bool jBetter = (kj > ki) || (kj == ki && vj < vi);
            if (up ? jBetter : !jBetter) {
                key[i] = kj; key[j] = ki;
                val[i] = vj; val[j] = vi;
            }
            __syncthreads();
        }
    }
    if (t < TOPK) topk[b * TOPK + t] = val[t];
}

// ---------------- edge Welsch loss per batch ----------------
__global__ __launch_bounds__(256)
void wl_edge_kernel(const float* __restrict__ src, const float* __restrict__ corr,
                    const int* __restrict__ topk, float* __restrict__ bloss) {
    __shared__ float sx[TOPK][3];
    __shared__ float tx[TOPK][3];
    __shared__ float lds[4];
    int b = blockIdx.x, t = threadIdx.x;
    if (t < TOPK) {
        int id = topk[b * TOPK + t];
        sx[t][0] = src[((size_t)b * 2048 + id) * 3 + 0];
        sx[t][1] = src[((size_t)b * 2048 + id) * 3 + 1];
        sx[t][2] = src[((size_t)b * 2048 + id) * 3 + 2];
        tx[t][0] = corr[((size_t)b * 2048 + id) * 3 + 0];
        tx[t][1] = corr[((size_t)b * 2048 + id) * 3 + 1];
        tx[t][2] = corr[((size_t)b * 2048 + id) * 3 + 2];
    }
    __syncthreads();
    float acc = 0.f;
    for (int p = t; p < TOPK * TOPK; p += 256) {
        int i = p >> 7, j = p & 127;
        float dx = sx[i][0] - sx[j][0], dy = sx[i][1] - sx[j][1], dz = sx[i][2] - sx[j][2];
        float d2s = dx * dx + dy * dy + dz * dz;
        float ds = d2s > 0.f ? sqrtf(d2s) : 0.f;
        float ex = tx[i][0] - tx[j][0], ey = tx[i][1] - tx[j][1], ez = tx[i][2] - tx[j][2];
        float d2t = ex * ex + ey * ey + ez * ez;
        float dt = d2t > 0.f ? sqrtf(d2t) : 0.f;
        float z = fabsf(ds - dt);
        acc += 1.f - expf(-0.5f * z * z);
    }
    int l = t & 63, w = t >> 6;
    for (int o = 32; o; o >>= 1) acc += __shfl_xor(acc, o);
    if (l == 0) lds[w] = acc;
    __syncthreads();
    if (t == 0) bloss[b] = lds[0] + lds[1] + lds[2] + lds[3];
}

__global__ void wl_final_kernel(const float* __restrict__ bloss, float* __restrict__ out) {
    if (threadIdx.x == 0) {
        float s = 0.f;
        for (int i = 0; i < Bb; i++) s += bloss[i];
        out[0] = s / 1024.f;   // mean over [B, K] = 8*128
    }
}

extern "C" void kernel_launch(void* const* d_in, const int* in_sizes, int n_in,
                              void* d_out, int out_size, void* d_ws, size_t ws_size,
                              hipStream_t stream) {
    (void)in_sizes; (void)n_in; (void)out_size;
    const float* src       = (const float*)d_in[0];
    const float* tgt       = (const float*)d_in[1];
    const float* src_feats = (const float*)d_in[2];
    const float* tgt_feats = (const float*)d_in[3];
    const float* src_o     = (const float*)d_in[4];
    const float* tgt_o     = (const float*)d_in[5];
    float* out = (float*)d_out;

    // choose nch so the workspace fits (nch=32 layout == round-1 proven size)
    size_t fixed = (size_t)Bb * Nn * Mm + 7 * (size_t)Bb * Nn + 3 * (size_t)Bb * Nn   // Sc + 7 small + corr
                 + (size_t)Bb * TOPK + Bb + 64;
    int nch = (ws_size >= (fixed + 2 * (size_t)Bb * 64 * Mm) * sizeof(float)) ? 64 : 32;

    float* ws = (float*)d_ws;
    size_t off = 0;
    float* Sc    = ws + off; off += (size_t)Bb * Nn * Mm;
    float* Ue    = ws + off; off += Bb * Nn;
    float* Ve    = ws + off; off += Bb * Mm;
    float* logp2 = ws + off; off += Bb * Nn;
    float* logq2 = ws + off; off += Bb * Mm;
    float* nx    = ws + off; off += Bb * Nn;
    float* ny    = ws + off; off += Bb * Mm;
    float* prob  = ws + off; off += Bb * Nn;
    float* corr  = ws + off; off += (size_t)Bb * Nn * 3;
    float* pmx   = ws + off; off += (size_t)Bb * nch * Mm;
    float* psm   = ws + off; off += (size_t)Bb * nch * Mm;
    int*   topk  = (int*)(ws + off); off += Bb * TOPK;
    float* bloss = ws + off; off += Bb;
    if (ws_size < off * sizeof(float)) return;  // should never happen (nch fallback)

    wl_init_kernel<<<Bb, 256, 0, stream>>>(src_o, tgt_o, logp2, logq2, Ve);
    wl_norms_kernel<<<(Bb * Nn) / 4, 256, 0, stream>>>(src_feats, nx);
    wl_norms_kernel<<<(Bb * Mm) / 4, 256, 0, stream>>>(tgt_feats, ny);
    wl_cost_kernel<<<dim3(Mm / BT, Nn / BT, Bb), 256, 0, stream>>>(src_feats, tgt_feats, nx, ny, Sc);

    for (int it = 0; it < SK_ITERS; it++) {
        wl_fused_kernel<<<dim3(nch, Bb), 512, 0, stream>>>(Sc, Ve, logp2, Ue, pmx, psm, nch);
        wl_v_combine_kernel<<<(Bb * Mm) / 64, 256, 0, stream>>>(pmx, psm, logq2, Ve, nch);
    }

    wl_finalize_kernel<<<(Bb * Nn) / 4, 256, 0, stream>>>(Sc, Ue, Ve, tgt, prob, corr);
    wl_topk_kernel<<<Bb, 1024, 0, stream>>>(prob, topk);
    wl_edge_kernel<<<Bb, 256, 0, stream>>>(src, corr, topk, bloss);
    wl_final_kernel<<<1, 64, 0, stream>>>(bloss, out);
}

// Round 12
// 1632.207 us; speedup vs baseline: 1.2202x; 1.2202x over previous
//
#include <hip/hip_runtime.h>
#include <math.h>

#define Bb 8
#define Nn 2048
#define Mm 2048
#define Dd 256
#define TOPK 128
#define SK_ITERS 20
#define NEG_INIT (-1e30f)
// -1/(eps*ln2): cost -> log2-domain scaled score
#define SCALE_L2 (-1442.6950408889634f)

// ---- branchless log2-domain LSE merge (HW-proven r6-r11): 1 exp2 ----
__device__ __forceinline__ void lse_merge(float& m, float& s, float m2, float s2) {
    float d = m2 - m;
    float e = exp2f(-fabsf(d));
    bool up = (d > 0.f);
    s = up ? fmaf(s, e, s2) : fmaf(s2, e, s);
    m = up ? m2 : m;
}

// ---------------- init: marginals -> log2 p / log2 q, Ve = 0 ----------------
__global__ void wl_init_kernel(const float* __restrict__ src_o, const float* __restrict__ tgt_o,
                               float* __restrict__ logp2, float* __restrict__ logq2,
                               float* __restrict__ Ve) {
    __shared__ float lds[8];
    int b = blockIdx.x, t = threadIdx.x;
    int l = t & 63, w = t >> 6;
    float s = 0.f, q = 0.f;
    for (int i = t; i < Nn; i += 256) s += src_o[b * Nn + i];
    for (int i = t; i < Mm; i += 256) q += tgt_o[b * Mm + i];
    for (int o = 32; o; o >>= 1) { s += __shfl_xor(s, o); q += __shfl_xor(q, o); }
    if (l == 0) { lds[w] = s; lds[4 + w] = q; }
    __syncthreads();
    float ssum = fmaxf(lds[0] + lds[1] + lds[2] + lds[3], 1e-4f);
    float qsum = fmaxf(lds[4] + lds[5] + lds[6] + lds[7], 1e-4f);
    float rs = 1.f / ssum, rq = 1.f / qsum;
    for (int i = t; i < Nn; i += 256) logp2[b * Nn + i] = log2f(src_o[b * Nn + i] * rs);
    for (int i = t; i < Mm; i += 256) { logq2[b * Mm + i] = log2f(tgt_o[b * Mm + i] * rq); Ve[b * Mm + i] = 0.f; }
}

// ---------------- squared row norms ----------------
__global__ void wl_norms_kernel(const float* __restrict__ feats, float* __restrict__ out) {
    int w = threadIdx.x >> 6, l = threadIdx.x & 63;
    int row = blockIdx.x * 4 + w;             // [0, B*2048)
    float4 f = ((const float4*)(feats + (size_t)row * Dd))[l];
    float s = f.x * f.x + f.y * f.y + f.z * f.z + f.w * f.w;
    for (int o = 32; o; o >>= 1) s += __shfl_xor(s, o);
    if (l == 0) out[row] = s;
}

// ---------------- cost GEMM: Sc = -||fx - fy|| / (eps*ln2)  (round-1, measured 245us) ----------------
#define BT 128
#define KT 32
#define LDT 132
__global__ __launch_bounds__(256)
void wl_cost_kernel(const float* __restrict__ A, const float* __restrict__ Bf,
                    const float* __restrict__ nx, const float* __restrict__ ny,
                    float* __restrict__ Sc) {
    __shared__ float As[KT][LDT];
    __shared__ float Bs[KT][LDT];
    int b = blockIdx.z;
    int n0 = blockIdx.y * BT, m0 = blockIdx.x * BT;
    const float* Ab = A + (size_t)b * Nn * Dd;
    const float* Bbp = Bf + (size_t)b * Mm * Dd;
    int t = threadIdx.x;
    int w = t >> 6, l = t & 63;
    int tx = (w & 1) * 8 + (l & 7);   // 0..15 col group
    int ty = (w >> 1) * 8 + (l >> 3); // 0..15 row group
    float acc[8][8] = {};
    for (int k0 = 0; k0 < Dd; k0 += KT) {
        __syncthreads();
#pragma unroll
        for (int i = 0; i < 4; i++) {
            int c = t + 256 * i;          // 0..1023
            int row = c >> 3, kc = (c & 7) << 2;
            float4 v = *(const float4*)(Ab + (size_t)(n0 + row) * Dd + k0 + kc);
            As[kc + 0][row] = v.x; As[kc + 1][row] = v.y; As[kc + 2][row] = v.z; As[kc + 3][row] = v.w;
            float4 u = *(const float4*)(Bbp + (size_t)(m0 + row) * Dd + k0 + kc);
            Bs[kc + 0][row] = u.x; Bs[kc + 1][row] = u.y; Bs[kc + 2][row] = u.z; Bs[kc + 3][row] = u.w;
        }
        __syncthreads();
#pragma unroll 4
        for (int k = 0; k < KT; k++) {
            float4 a0 = *(const float4*)&As[k][ty * 8];
            float4 a1 = *(const float4*)&As[k][ty * 8 + 4];
            float4 b0 = *(const float4*)&Bs[k][tx * 8];
            float4 b1 = *(const float4*)&Bs[k][tx * 8 + 4];
            float a[8] = { a0.x, a0.y, a0.z, a0.w, a1.x, a1.y, a1.z, a1.w };
            float bv[8] = { b0.x, b0.y, b0.z, b0.w, b1.x, b1.y, b1.z, b1.w };
#pragma unroll
            for (int i = 0; i < 8; i++)
#pragma unroll
                for (int j = 0; j < 8; j++)
                    acc[i][j] = fmaf(a[i], bv[j], acc[i][j]);
        }
    }
    float nyv[8];
#pragma unroll
    for (int j = 0; j < 8; j++) nyv[j] = ny[b * Mm + m0 + tx * 8 + j];
#pragma unroll
    for (int i = 0; i < 8; i++) {
        int n = n0 + ty * 8 + i;
        float nxv = nx[b * Nn + n];
        float o[8];
#pragma unroll
        for (int j = 0; j < 8; j++) {
            float d2 = nxv + nyv[j] - 2.f * acc[i][j];
            d2 = fmaxf(d2, 0.f);
            float c = d2 > 0.f ? sqrtf(d2) : 0.f;
            o[j] = SCALE_L2 * c;
        }
        float* orow = Sc + ((size_t)b * Nn + n) * Mm + m0 + tx * 8;
        *(float4*)orow = make_float4(o[0], o[1], o[2], o[3]);
        *(float4*)(orow + 4) = make_float4(o[4], o[5], o[6], o[7]);
    }
}

// ---------------- u-update: round-1 geometry, two-phase LSE (1 exp2/elem) ----------------
// wave per row, lane l holds cols {4l+256i}; tv[8] float4 statically indexed (~45 VGPR).
__global__ __launch_bounds__(256)
void wl_u_kernel(const float* __restrict__ Sc, const float* __restrict__ Ve,
                 const float* __restrict__ logp2, float* __restrict__ Ue) {
    int w = threadIdx.x >> 6, l = threadIdx.x & 63;
    int row = blockIdx.x * 4 + w;         // [0, B*N)
    int b = row >> 11;
    const float4* s4 = (const float4*)(Sc + (size_t)row * Mm);
    const float4* v4 = (const float4*)(Ve + (size_t)b * Mm);
    float4 tv[8];
#pragma unroll
    for (int i = 0; i < 8; i++) {
        float4 sv = s4[l + 64 * i];
        float4 vv = v4[l + 64 * i];
        tv[i].x = sv.x + vv.x; tv[i].y = sv.y + vv.y;
        tv[i].z = sv.z + vv.z; tv[i].w = sv.w + vv.w;
    }
    float mx = tv[0].x;
#pragma unroll
    for (int i = 0; i < 8; i++) {
        mx = fmaxf(mx, fmaxf(fmaxf(tv[i].x, tv[i].y), fmaxf(tv[i].z, tv[i].w)));
    }
    for (int o = 32; o; o >>= 1) mx = fmaxf(mx, __shfl_xor(mx, o));
    float sm = 0.f;
#pragma unroll
    for (int i = 0; i < 8; i++) {
        sm += exp2f(tv[i].x - mx) + exp2f(tv[i].y - mx)
            + exp2f(tv[i].z - mx) + exp2f(tv[i].w - mx);
    }
    for (int o = 32; o; o >>= 1) sm += __shfl_xor(sm, o);
    if (l == 0) Ue[row] = logp2[row] - mx - log2f(sm);
}

// ---------------- v-update partials: round-1 geometry, lse_merge (1 exp2/elem) ----------------
__global__ __launch_bounds__(256)
void wl_v_partial_kernel(const float* __restrict__ Sc, const float* __restrict__ Ue,
                         float* __restrict__ pmx, float* __restrict__ psm, int nch) {
    int b = blockIdx.z, ch = blockIdx.y;
    int m0 = blockIdx.x * 1024 + threadIdx.x * 4;
    const float* base = Sc + (size_t)b * Nn * Mm;
    const float* ue = Ue + b * Nn;
    float cm0 = NEG_INIT, cm1 = NEG_INIT, cm2 = NEG_INIT, cm3 = NEG_INIT;
    float cs0 = 0.f, cs1 = 0.f, cs2 = 0.f, cs3 = 0.f;
    int chrows = Nn / nch;
    int nst = ch * chrows;
#pragma unroll 4
    for (int n = nst; n < nst + chrows; n++) {
        float u = ue[n];
        float4 sv = *(const float4*)(base + (size_t)n * Mm + m0);
        lse_merge(cm0, cs0, sv.x + u, 1.f);
        lse_merge(cm1, cs1, sv.y + u, 1.f);
        lse_merge(cm2, cs2, sv.z + u, 1.f);
        lse_merge(cm3, cs3, sv.w + u, 1.f);
    }
    size_t pi = ((size_t)(b * nch + ch)) * Mm + m0;
    *(float4*)(pmx + pi) = make_float4(cm0, cm1, cm2, cm3);
    *(float4*)(psm + pi) = make_float4(cs0, cs1, cs2, cs3);
}

// ---------------- v-combine: Ve = logq2 - LSE (round-1 algebra, lse_merge) ----------------
__global__ void wl_v_combine_kernel(const float* __restrict__ pmx, const float* __restrict__ psm,
                                    const float* __restrict__ logq2, float* __restrict__ Ve, int nch) {
    int idx = blockIdx.x * 256 + threadIdx.x;   // b*M + m
    int b = idx >> 11, m = idx & (Mm - 1);
    const float* pbm = pmx + (size_t)b * nch * Mm + m;
    const float* pbs = psm + (size_t)b * nch * Mm + m;
    float mx = NEG_INIT, sm = 0.f;
    for (int ch = 0; ch < nch; ch++)
        lse_merge(mx, sm, pbm[(size_t)ch * Mm], pbs[(size_t)ch * Mm]);
    Ve[idx] = logq2[idx] - mx - log2f(sm);
}

// ---------------- finalize: prob = max gamma, corr = (gamma@tgt)/clip(rowsum) ----------------
__global__ __launch_bounds__(256)
void wl_finalize_kernel(const float* __restrict__ Sc, const float* __restrict__ Ue,
                        const float* __restrict__ Ve, const float* __restrict__ tgt,
                        float* __restrict__ prob, float* __restrict__ corr) {
    int w = threadIdx.x >> 6, l = threadIdx.x & 63;
    int row = blockIdx.x * 4 + w;
    int b = row >> 11;
    const float4* s4 = (const float4*)(Sc + (size_t)row * Mm);
    const float4* v4 = (const float4*)(Ve + (size_t)b * Mm);
    const float4* tg4 = (const float4*)(tgt + (size_t)b * Mm * 3);
    float mx = NEG_INIT, sm = 0.f, w0 = 0.f, w1 = 0.f, w2 = 0.f;
#pragma unroll
    for (int i = 0; i < 8; i++) {
        int c = l + 64 * i;
        float4 sv = s4[c]; float4 vv = v4[c];
        float4 g0 = tg4[3 * c + 0], g1 = tg4[3 * c + 1], g2 = tg4[3 * c + 2];
        float tt[4] = { sv.x + vv.x, sv.y + vv.y, sv.z + vv.z, sv.w + vv.w };
        float gx[4] = { g0.x, g0.w, g1.z, g2.y };
        float gy[4] = { g0.y, g1.x, g1.w, g2.z };
        float gz[4] = { g0.z, g1.y, g2.x, g2.w };
#pragma unroll
        for (int j = 0; j < 4; j++) {
            float nm = fmaxf(mx, tt[j]);
            float ce = exp2f(mx - nm), e = exp2f(tt[j] - nm);
            sm = sm * ce + e;
            w0 = w0 * ce + e * gx[j];
            w1 = w1 * ce + e * gy[j];
            w2 = w2 * ce + e * gz[j];
            mx = nm;
        }
    }
    for (int o = 32; o; o >>= 1) {
        float om = __shfl_xor(mx, o), os = __shfl_xor(sm, o);
        float o0 = __shfl_xor(w0, o), o1 = __shfl_xor(w1, o), o2 = __shfl_xor(w2, o);
        float nm = fmaxf(mx, om);
        float c1 = exp2f(mx - nm), c2 = exp2f(om - nm);
        sm = sm * c1 + os * c2;
        w0 = w0 * c1 + o0 * c2;
        w1 = w1 * c1 + o1 * c2;
        w2 = w2 * c1 + o2 * c2;
        mx = nm;
    }
    if (l == 0) {
        float scale = exp2f(Ue[row] + mx);   // = max_m gamma
        float rowsum = scale * sm;
        float den = fmaxf(rowsum, 1e-4f);
        prob[row] = scale;
        corr[(size_t)row * 3 + 0] = scale * w0 / den;
        corr[(size_t)row * 3 + 1] = scale * w1 / den;
        corr[(size_t)row * 3 + 2] = scale * w2 / den;
    }
}

// ---------------- top-k via bitonic sort (round-1 256-thread version) ----------------
__global__ __launch_bounds__(256)
void wl_topk_kernel(const float* __restrict__ prob, int* __restrict__ topk) {
    __shared__ float key[2048];
    __shared__ int val[2048];
    int b = blockIdx.x, t = threadIdx.x;
    for (int i = t; i < 2048; i += 256) { key[i] = prob[b * 2048 + i]; val[i] = i; }
    __syncthreads();
    for (int size = 2; size <= 2048; size <<= 1) {
        for (int stride = size >> 1; stride > 0; stride >>= 1) {
            for (int q = t; q < 1024; q += 256) {
                int i = 2 * q - (q & (stride - 1));
                int j = i + stride;
                bool up = ((i & size) == 0);
                float ki = key[i], kj = key[j];
                int vi = val[i], vj = val[j];
                bool jBetter = (kj > ki) || (kj == ki && vj < vi);
                if (up ? jBetter : !jBetter) {
                    key[i] = kj; key[j] = ki;
                    val[i] = vj; val[j] = vi;
                }
            }
            __syncthreads();
        }
    }
    if (t < TOPK) topk[b * TOPK + t] = val[t];
}

// ---------------- edge Welsch loss per batch ----------------
__global__ __launch_bounds__(256)
void wl_edge_kernel(const float* __restrict__ src, const float* __restrict__ corr,
                    const int* __restrict__ topk, float* __restrict__ bloss) {
    __shared__ float sx[TOPK][3];
    __shared__ float tx[TOPK][3];
    __shared__ float lds[4];
    int b = blockIdx.x, t = threadIdx.x;
    if (t < TOPK) {
        int id = topk[b * TOPK + t];
        sx[t][0] = src[((size_t)b * 2048 + id) * 3 + 0];
        sx[t][1] = src[((size_t)b * 2048 + id) * 3 + 1];
        sx[t][2] = src[((size_t)b * 2048 + id) * 3 + 2];
        tx[t][0] = corr[((size_t)b * 2048 + id) * 3 + 0];
        tx[t][1] = corr[((size_t)b * 2048 + id) * 3 + 1];
        tx[t][2] = corr[((size_t)b * 2048 + id) * 3 + 2];
    }
    __syncthreads();
    float acc = 0.f;
    for (int p = t; p < TOPK * TOPK; p += 256) {
        int i = p >> 7, j = p & 127;
        float dx = sx[i][0] - sx[j][0], dy = sx[i][1] - sx[j][1], dz = sx[i][2] - sx[j][2];
        float d2s = dx * dx + dy * dy + dz * dz;
        float ds = d2s > 0.f ? sqrtf(d2s) : 0.f;
        float ex = tx[i][0] - tx[j][0], ey = tx[i][1] - tx[j][1], ez = tx[i][2] - tx[j][2];
        float d2t = ex * ex + ey * ey + ez * ez;
        float dt = d2t > 0.f ? sqrtf(d2t) : 0.f;
        float z = fabsf(ds - dt);
        acc += 1.f - expf(-0.5f * z * z);
    }
    int l = t & 63, w = t >> 6;
    for (int o = 32; o; o >>= 1) acc += __shfl_xor(acc, o);
    if (l == 0) lds[w] = acc;
    __syncthreads();
    if (t == 0) bloss[b] = lds[0] + lds[1] + lds[2] + lds[3];
}

__global__ void wl_final_kernel(const float* __restrict__ bloss, float* __restrict__ out) {
    if (threadIdx.x == 0) {
        float s = 0.f;
        for (int i = 0; i < Bb; i++) s += bloss[i];
        out[0] = s / 1024.f;   // mean over [B, K] = 8*128
    }
}

extern "C" void kernel_launch(void* const* d_in, const int* in_sizes, int n_in,
                              void* d_out, int out_size, void* d_ws, size_t ws_size,
                              hipStream_t stream) {
    (void)in_sizes; (void)n_in; (void)out_size;
    const float* src       = (const float*)d_in[0];
    const float* tgt       = (const float*)d_in[1];
    const float* src_feats = (const float*)d_in[2];
    const float* tgt_feats = (const float*)d_in[3];
    const float* src_o     = (const float*)d_in[4];
    const float* tgt_o     = (const float*)d_in[5];
    float* out = (float*)d_out;

    // choose nch so the workspace fits (nch=32 layout == round-1 proven size)
    size_t fixed = (size_t)Bb * Nn * Mm + 7 * (size_t)Bb * Nn + 3 * (size_t)Bb * Nn
                 + (size_t)Bb * TOPK + Bb + 64;
    int nch = (ws_size >= (fixed + 2 * (size_t)Bb * 64 * Mm) * sizeof(float)) ? 64 : 32;

    float* ws = (float*)d_ws;
    size_t off = 0;
    float* Sc    = ws + off; off += (size_t)Bb * Nn * Mm;
    float* Ue    = ws + off; off += Bb * Nn;
    float* Ve    = ws + off; off += Bb * Mm;
    float* logp2 = ws + off; off += Bb * Nn;
    float* logq2 = ws + off; off += Bb * Mm;
    float* nx    = ws + off; off += Bb * Nn;
    float* ny    = ws + off; off += Bb * Mm;
    float* prob  = ws + off; off += Bb * Nn;
    float* corr  = ws + off; off += (size_t)Bb * Nn * 3;
    float* pmx   = ws + off; off += (size_t)Bb * nch * Mm;
    float* psm   = ws + off; off += (size_t)Bb * nch * Mm;
    int*   topk  = (int*)(ws + off); off += Bb * TOPK;
    float* bloss = ws + off; off += Bb;
    if (ws_size < off * sizeof(float)) return;

    wl_init_kernel<<<Bb, 256, 0, stream>>>(src_o, tgt_o, logp2, logq2, Ve);
    wl_norms_kernel<<<(Bb * Nn) / 4, 256, 0, stream>>>(src_feats, nx);
    wl_norms_kernel<<<(Bb * Mm) / 4, 256, 0, stream>>>(tgt_feats, ny);
    wl_cost_kernel<<<dim3(Mm / BT, Nn / BT, Bb), 256, 0, stream>>>(src_feats, tgt_feats, nx, ny, Sc);

    for (int it = 0; it < SK_ITERS; it++) {
        wl_u_kernel<<<(Bb * Nn) / 4, 256, 0, stream>>>(Sc, Ve, logp2, Ue);
        wl_v_partial_kernel<<<dim3(Mm / 1024, nch, Bb), 256, 0, stream>>>(Sc, Ue, pmx, psm, nch);
        wl_v_combine_kernel<<<(Bb * Mm) / 256, 256, 0, stream>>>(pmx, psm, logq2, Ve, nch);
    }

    wl_finalize_kernel<<<(Bb * Nn) / 4, 256, 0, stream>>>(Sc, Ue, Ve, tgt, prob, corr);
    wl_topk_kernel<<<Bb, 256, 0, stream>>>(prob, topk);
    wl_edge_kernel<<<Bb, 256, 0, stream>>>(src, corr, topk, bloss);
    wl_final_kernel<<<1, 64, 0, stream>>>(bloss, out);
}

// Round 13
// 1363.273 us; speedup vs baseline: 1.4609x; 1.1973x over previous
//
#include <hip/hip_runtime.h>
#include <math.h>

#define Bb 8
#define Nn 2048
#define Mm 2048
#define Dd 256
#define TOPK 128
#define SK_ITERS 20
#define NCH 32            // n-chunks for v-update partials (round-1 proven)
#define CHROWS (Nn/NCH)   // 64
#define NEG_INIT (-1e30f)
// -1/(eps*ln2): cost -> log2-domain scaled score
#define SCALE_L2 (-1442.6950408889634f)

typedef _Float16 half8 __attribute__((ext_vector_type(8)));
typedef float f32x4 __attribute__((ext_vector_type(4)));

// ---------------- init: marginals -> log2 p / log2 q, Ve = 0 ----------------
__global__ void wl_init_kernel(const float* __restrict__ src_o, const float* __restrict__ tgt_o,
                               float* __restrict__ logp2, float* __restrict__ logq2,
                               float* __restrict__ Ve) {
    __shared__ float lds[8];
    int b = blockIdx.x, t = threadIdx.x;
    int l = t & 63, w = t >> 6;
    float s = 0.f, q = 0.f;
    for (int i = t; i < Nn; i += 256) s += src_o[b * Nn + i];
    for (int i = t; i < Mm; i += 256) q += tgt_o[b * Mm + i];
    for (int o = 32; o; o >>= 1) { s += __shfl_xor(s, o); q += __shfl_xor(q, o); }
    if (l == 0) { lds[w] = s; lds[4 + w] = q; }
    __syncthreads();
    float ssum = fmaxf(lds[0] + lds[1] + lds[2] + lds[3], 1e-4f);
    float qsum = fmaxf(lds[4] + lds[5] + lds[6] + lds[7], 1e-4f);
    float rs = 1.f / ssum, rq = 1.f / qsum;
    for (int i = t; i < Nn; i += 256) logp2[b * Nn + i] = log2f(src_o[b * Nn + i] * rs);
    for (int i = t; i < Mm; i += 256) { logq2[b * Mm + i] = log2f(tgt_o[b * Mm + i] * rq); Ve[b * Mm + i] = 0.f; }
}

// ---------------- squared row norms ----------------
__global__ void wl_norms_kernel(const float* __restrict__ feats, float* __restrict__ out) {
    int w = threadIdx.x >> 6, l = threadIdx.x & 63;
    int row = blockIdx.x * 4 + w;             // [0, B*2048)
    float4 f = ((const float4*)(feats + (size_t)row * Dd))[l];
    float s = f.x * f.x + f.y * f.y + f.z * f.z + f.w * f.w;
    for (int o = 32; o; o >>= 1) s += __shfl_xor(s, o);
    if (l == 0) out[row] = s;
}

// ---------------- cost GEMM via f16 hi/lo split MFMA ----------------
// G = A.B^T computed as acc1(ah.bh) + acc2(ah.bl' + al'.bh)/2048,
// ah = fp32 mantissa-truncated to 11 bits (exact f16), al' = 2048*(a-ah) as f16.
// Block 64x128: 4 waves, wave w owns rows [w*16,w*16+16) x 128 cols (8 subtiles).
// Fragment layouts (m89/m91 + CDNA matrix calc):
//  A: row=lane&15, k=(lane>>4)*8+i ; B: col=lane&15, k=(lane>>4)*8+i
//  D: row=(lane>>4)*4+reg, col=lane&15
#define CBM 64
#define CBN 128
#define CKT 32
#define HPITCH 40   // halves; 80B rows -> 16B-aligned half8 reads
__global__ __launch_bounds__(256)
void wl_cost_kernel(const float* __restrict__ A, const float* __restrict__ Bf,
                    const float* __restrict__ nx, const float* __restrict__ ny,
                    float* __restrict__ Sc) {
    __shared__ _Float16 Ah[CBM][HPITCH], Al[CBM][HPITCH];
    __shared__ _Float16 Bh[CBN][HPITCH], Bl[CBN][HPITCH];
    int b = blockIdx.z;
    int n0 = blockIdx.y * CBM, m0 = blockIdx.x * CBN;
    const float* Ab = A + (size_t)b * Nn * Dd;
    const float* Bbp = Bf + (size_t)b * Mm * Dd;
    int t = threadIdx.x, w = t >> 6, l = t & 63;

    f32x4 acc1[8], acc2[8];
#pragma unroll
    for (int c = 0; c < 8; c++) {
        acc1[c] = (f32x4){0.f, 0.f, 0.f, 0.f};
        acc2[c] = (f32x4){0.f, 0.f, 0.f, 0.f};
    }

    for (int k0 = 0; k0 < Dd; k0 += CKT) {
        __syncthreads();
        // stage A panel: 64 rows x 32 k = 512 float4 -> 2 per thread
#pragma unroll
        for (int i = 0; i < 2; i++) {
            int idx = t + 256 * i;
            int row = idx >> 3, kc = (idx & 7) << 2;
            float4 v = *(const float4*)(Ab + (size_t)(n0 + row) * Dd + k0 + kc);
            float h0 = __uint_as_float(__float_as_uint(v.x) & 0xFFFFE000u);
            float h1 = __uint_as_float(__float_as_uint(v.y) & 0xFFFFE000u);
            float h2 = __uint_as_float(__float_as_uint(v.z) & 0xFFFFE000u);
            float h3 = __uint_as_float(__float_as_uint(v.w) & 0xFFFFE000u);
            Ah[row][kc + 0] = (_Float16)h0; Al[row][kc + 0] = (_Float16)((v.x - h0) * 2048.f);
            Ah[row][kc + 1] = (_Float16)h1; Al[row][kc + 1] = (_Float16)((v.y - h1) * 2048.f);
            Ah[row][kc + 2] = (_Float16)h2; Al[row][kc + 2] = (_Float16)((v.z - h2) * 2048.f);
            Ah[row][kc + 3] = (_Float16)h3; Al[row][kc + 3] = (_Float16)((v.w - h3) * 2048.f);
        }
        // stage B panel: 128 rows x 32 k = 1024 float4 -> 4 per thread
#pragma unroll
        for (int i = 0; i < 4; i++) {
            int idx = t + 256 * i;
            int row = idx >> 3, kc = (idx & 7) << 2;
            float4 v = *(const float4*)(Bbp + (size_t)(m0 + row) * Dd + k0 + kc);
            float h0 = __uint_as_float(__float_as_uint(v.x) & 0xFFFFE000u);
            float h1 = __uint_as_float(__float_as_uint(v.y) & 0xFFFFE000u);
            float h2 = __uint_as_float(__float_as_uint(v.z) & 0xFFFFE000u);
            float h3 = __uint_as_float(__float_as_uint(v.w) & 0xFFFFE000u);
            Bh[row][kc + 0] = (_Float16)h0; Bl[row][kc + 0] = (_Float16)((v.x - h0) * 2048.f);
            Bh[row][kc + 1] = (_Float16)h1; Bl[row][kc + 1] = (_Float16)((v.y - h1) * 2048.f);
            Bh[row][kc + 2] = (_Float16)h2; Bl[row][kc + 2] = (_Float16)((v.z - h2) * 2048.f);
            Bh[row][kc + 3] = (_Float16)h3; Bl[row][kc + 3] = (_Float16)((v.w - h3) * 2048.f);
        }
        __syncthreads();

        int arow = w * 16 + (l & 15);
        int kb = (l >> 4) * 8;
        half8 ah = *(const half8*)&Ah[arow][kb];
        half8 al = *(const half8*)&Al[arow][kb];
#pragma unroll
        for (int c = 0; c < 8; c++) {
            int brow = c * 16 + (l & 15);
            half8 bh = *(const half8*)&Bh[brow][kb];
            half8 bl = *(const half8*)&Bl[brow][kb];
            acc1[c] = __builtin_amdgcn_mfma_f32_16x16x32_f16(ah, bh, acc1[c], 0, 0, 0);
            acc2[c] = __builtin_amdgcn_mfma_f32_16x16x32_f16(ah, bl, acc2[c], 0, 0, 0);
            acc2[c] = __builtin_amdgcn_mfma_f32_16x16x32_f16(al, bh, acc2[c], 0, 0, 0);
        }
    }

    // epilogue: lane holds D rows (l>>4)*4+r, col l&15 per subtile
    int rbase = n0 + w * 16 + (l >> 4) * 4;
    float nxv[4];
#pragma unroll
    for (int r = 0; r < 4; r++) nxv[r] = nx[b * Nn + rbase + r];
#pragma unroll
    for (int c = 0; c < 8; c++) {
        int col = m0 + c * 16 + (l & 15);
        float nyv = ny[b * Mm + col];
#pragma unroll
        for (int r = 0; r < 4; r++) {
            float G = acc1[c][r] + acc2[c][r] * (1.f / 2048.f);
            float d2 = nxv[r] + nyv - 2.f * G;
            d2 = fmaxf(d2, 0.f);
            float cd = d2 > 0.f ? sqrtf(d2) : 0.f;
            Sc[((size_t)b * Nn + rbase + r) * Mm + col] = SCALE_L2 * cd;
        }
    }
}

// ---------------- u-update (round-1 verbatim): Ue = logp2 - LSE2_m(Sc + Ve) ----------------
__global__ __launch_bounds__(256)
void wl_u_kernel(const float* __restrict__ Sc, const float* __restrict__ Ve,
                 const float* __restrict__ logp2, float* __restrict__ Ue) {
    int w = threadIdx.x >> 6, l = threadIdx.x & 63;
    int row = blockIdx.x * 4 + w;         // [0, B*N)
    int b = row >> 11;
    const float4* s4 = (const float4*)(Sc + (size_t)row * Mm);
    const float4* v4 = (const float4*)(Ve + (size_t)b * Mm);
    float mx0 = NEG_INIT, mx1 = NEG_INIT, mx2 = NEG_INIT, mx3 = NEG_INIT;
    float sm0 = 0.f, sm1 = 0.f, sm2 = 0.f, sm3 = 0.f;
#pragma unroll
    for (int i = 0; i < 8; i++) {
        int c = l + 64 * i;
        float4 sv = s4[c]; float4 vv = v4[c];
        float t0 = sv.x + vv.x, t1 = sv.y + vv.y, t2 = sv.z + vv.z, t3 = sv.w + vv.w;
        float n0 = fmaxf(mx0, t0); sm0 = sm0 * exp2f(mx0 - n0) + exp2f(t0 - n0); mx0 = n0;
        float n1 = fmaxf(mx1, t1); sm1 = sm1 * exp2f(mx1 - n1) + exp2f(t1 - n1); mx1 = n1;
        float n2 = fmaxf(mx2, t2); sm2 = sm2 * exp2f(mx2 - n2) + exp2f(t2 - n2); mx2 = n2;
        float n3 = fmaxf(mx3, t3); sm3 = sm3 * exp2f(mx3 - n3) + exp2f(t3 - n3); mx3 = n3;
    }
    float mx = fmaxf(fmaxf(mx0, mx1), fmaxf(mx2, mx3));
    float sm = sm0 * exp2f(mx0 - mx) + sm1 * exp2f(mx1 - mx) + sm2 * exp2f(mx2 - mx) + sm3 * exp2f(mx3 - mx);
    for (int o = 32; o; o >>= 1) {
        float om = __shfl_xor(mx, o), os = __shfl_xor(sm, o);
        float nm = fmaxf(mx, om);
        sm = sm * exp2f(mx - nm) + os * exp2f(om - nm);
        mx = nm;
    }
    if (l == 0) Ue[row] = logp2[row] - (mx + log2f(sm));
}

// ---------------- v-update partials (round-1 verbatim) ----------------
__global__ __launch_bounds__(256)
void wl_v_partial_kernel(const float* __restrict__ Sc, const float* __restrict__ Ue,
                         float* __restrict__ pmx, float* __restrict__ psm) {
    int b = blockIdx.z, ch = blockIdx.y;
    int m0 = blockIdx.x * 1024 + threadIdx.x * 4;
    const float* base = Sc + (size_t)b * Nn * Mm;
    const float* ue = Ue + b * Nn;
    float mx0 = NEG_INIT, mx1 = NEG_INIT, mx2 = NEG_INIT, mx3 = NEG_INIT;
    float sm0 = 0.f, sm1 = 0.f, sm2 = 0.f, sm3 = 0.f;
    int nst = ch * CHROWS;
#pragma unroll 4
    for (int n = nst; n < nst + CHROWS; n++) {
        float u = ue[n];
        float4 sv = *(const float4*)(base + (size_t)n * Mm + m0);
        float t0 = sv.x + u, t1 = sv.y + u, t2 = sv.z + u, t3 = sv.w + u;
        float n0 = fmaxf(mx0, t0); sm0 = sm0 * exp2f(mx0 - n0) + exp2f(t0 - n0); mx0 = n0;
        float n1 = fmaxf(mx1, t1); sm1 = sm1 * exp2f(mx1 - n1) + exp2f(t1 - n1); mx1 = n1;
        float n2 = fmaxf(mx2, t2); sm2 = sm2 * exp2f(mx2 - n2) + exp2f(t2 - n2); mx2 = n2;
        float n3 = fmaxf(mx3, t3); sm3 = sm3 * exp2f(mx3 - n3) + exp2f(t3 - n3); mx3 = n3;
    }
    size_t pi = ((size_t)(b * NCH + ch)) * Mm + m0;
    *(float4*)(pmx + pi) = make_float4(mx0, mx1, mx2, mx3);
    *(float4*)(psm + pi) = make_float4(sm0, sm1, sm2, sm3);
}

// ---------------- v-combine (round-1 verbatim) ----------------
__global__ void wl_v_combine_kernel(const float* __restrict__ pmx, const float* __restrict__ psm,
                                    const float* __restrict__ logq2, float* __restrict__ Ve) {
    int idx = blockIdx.x * 256 + threadIdx.x;   // b*M + m
    int b = idx >> 11, m = idx & (Mm - 1);
    float mx = NEG_INIT, sm = 0.f;
#pragma unroll
    for (int ch = 0; ch < NCH; ch++) {
        float om = pmx[((size_t)(b * NCH + ch)) * Mm + m];
        float os = psm[((size_t)(b * NCH + ch)) * Mm + m];
        float nm = fmaxf(mx, om);
        sm = sm * exp2f(mx - nm) + os * exp2f(om - nm);
        mx = nm;
    }
    Ve[idx] = logq2[idx] - (mx + log2f(sm));
}

// ---------------- finalize (round-1 verbatim) ----------------
__global__ __launch_bounds__(256)
void wl_finalize_kernel(const float* __restrict__ Sc, const float* __restrict__ Ue,
                        const float* __restrict__ Ve, const float* __restrict__ tgt,
                        float* __restrict__ prob, float* __restrict__ corr) {
    int w = threadIdx.x >> 6, l = threadIdx.x & 63;
    int row = blockIdx.x * 4 + w;
    int b = row >> 11;
    const float4* s4 = (const float4*)(Sc + (size_t)row * Mm);
    const float4* v4 = (const float4*)(Ve + (size_t)b * Mm);
    const float4* tg4 = (const float4*)(tgt + (size_t)b * Mm * 3);
    float mx = NEG_INIT, sm = 0.f, w0 = 0.f, w1 = 0.f, w2 = 0.f;
#pragma unroll
    for (int i = 0; i < 8; i++) {
        int c = l + 64 * i;
        float4 sv = s4[c]; float4 vv = v4[c];
        float4 g0 = tg4[3 * c + 0], g1 = tg4[3 * c + 1], g2 = tg4[3 * c + 2];
        float tt[4] = { sv.x + vv.x, sv.y + vv.y, sv.z + vv.z, sv.w + vv.w };
        float gx[4] = { g0.x, g0.w, g1.z, g2.y };
        float gy[4] = { g0.y, g1.x, g1.w, g2.z };
        float gz[4] = { g0.z, g1.y, g2.x, g2.w };
#pragma unroll
        for (int j = 0; j < 4; j++) {
            float nm = fmaxf(mx, tt[j]);
            float ce = exp2f(mx - nm), e = exp2f(tt[j] - nm);
            sm = sm * ce + e;
            w0 = w0 * ce + e * gx[j];
            w1 = w1 * ce + e * gy[j];
            w2 = w2 * ce + e * gz[j];
            mx = nm;
        }
    }
    for (int o = 32; o; o >>= 1) {
        float om = __shfl_xor(mx, o), os = __shfl_xor(sm, o);
        float o0 = __shfl_xor(w0, o), o1 = __shfl_xor(w1, o), o2 = __shfl_xor(w2, o);
        float nm = fmaxf(mx, om);
        float c1 = exp2f(mx - nm), c2 = exp2f(om - nm);
        sm = sm * c1 + os * c2;
        w0 = w0 * c1 + o0 * c2;
        w1 = w1 * c1 + o1 * c2;
        w2 = w2 * c1 + o2 * c2;
        mx = nm;
    }
    if (l == 0) {
        float scale = exp2f(Ue[row] + mx);   // = max_m gamma
        float rowsum = scale * sm;
        float den = fmaxf(rowsum, 1e-4f);
        prob[row] = scale;
        corr[(size_t)row * 3 + 0] = scale * w0 / den;
        corr[(size_t)row * 3 + 1] = scale * w1 / den;
        corr[(size_t)row * 3 + 2] = scale * w2 / den;
    }
}

// ---------------- top-k via bitonic sort (round-1 verbatim) ----------------
__global__ __launch_bounds__(256)
void wl_topk_kernel(const float* __restrict__ prob, int* __restrict__ topk) {
    __shared__ float key[2048];
    __shared__ int val[2048];
    int b = blockIdx.x, t = threadIdx.x;
    for (int i = t; i < 2048; i += 256) { key[i] = prob[b * 2048 + i]; val[i] = i; }
    __syncthreads();
    for (int size = 2; size <= 2048; size <<= 1) {
        for (int stride = size >> 1; stride > 0; stride >>= 1) {
            for (int q = t; q < 1024; q += 256) {
                int i = 2 * q - (q & (stride - 1));
                int j = i + stride;
                bool up = ((i & size) == 0);
                float ki = key[i], kj = key[j];
                int vi = val[i], vj = val[j];
                bool jBetter = (kj > ki) || (kj == ki && vj < vi);
                if (up ? jBetter : !jBetter) {
                    key[i] = kj; key[j] = ki;
                    val[i] = vj; val[j] = vi;
                }
            }
            __syncthreads();
        }
    }
    if (t < TOPK) topk[b * TOPK + t] = val[t];
}

// ---------------- edge Welsch loss per batch (round-1 verbatim) ----------------
__global__ __launch_bounds__(256)
void wl_edge_kernel(const float* __restrict__ src, const float* __restrict__ corr,
                    const int* __restrict__ topk, float* __restrict__ bloss) {
    __shared__ float sx[TOPK][3];
    __shared__ float tx[TOPK][3];
    __shared__ float lds[4];
    int b = blockIdx.x, t = threadIdx.x;
    if (t < TOPK) {
        int id = topk[b * TOPK + t];
        sx[t][0] = src[((size_t)b * 2048 + id) * 3 + 0];
        sx[t][1] = src[((size_t)b * 2048 + id) * 3 + 1];
        sx[t][2] = src[((size_t)b * 2048 + id) * 3 + 2];
        tx[t][0] = corr[((size_t)b * 2048 + id) * 3 + 0];
        tx[t][1] = corr[((size_t)b * 2048 + id) * 3 + 1];
        tx[t][2] = corr[((size_t)b * 2048 + id) * 3 + 2];
    }
    __syncthreads();
    float acc = 0.f;
    for (int p = t; p < TOPK * TOPK; p += 256) {
        int i = p >> 7, j = p & 127;
        float dx = sx[i][0] - sx[j][0], dy = sx[i][1] - sx[j][1], dz = sx[i][2] - sx[j][2];
        float d2s = dx * dx + dy * dy + dz * dz;
        float ds = d2s > 0.f ? sqrtf(d2s) : 0.f;
        float ex = tx[i][0] - tx[j][0], ey = tx[i][1] - tx[j][1], ez = tx[i][2] - tx[j][2];
        float d2t = ex * ex + ey * ey + ez * ez;
        float dt = d2t > 0.f ? sqrtf(d2t) : 0.f;
        float z = fabsf(ds - dt);
        acc += 1.f - expf(-0.5f * z * z);
    }
    int l = t & 63, w = t >> 6;
    for (int o = 32; o; o >>= 1) acc += __shfl_xor(acc, o);
    if (l == 0) lds[w] = acc;
    __syncthreads();
    if (t == 0) bloss[b] = lds[0] + lds[1] + lds[2] + lds[3];
}

__global__ void wl_final_kernel(const float* __restrict__ bloss, float* __restrict__ out) {
    if (threadIdx.x == 0) {
        float s = 0.f;
        for (int i = 0; i < Bb; i++) s += bloss[i];
        out[0] = s / 1024.f;   // mean over [B, K] = 8*128
    }
}

extern "C" void kernel_launch(void* const* d_in, const int* in_sizes, int n_in,
                              void* d_out, int out_size, void* d_ws, size_t ws_size,
                              hipStream_t stream) {
    (void)in_sizes; (void)n_in; (void)out_size;
    const float* src       = (const float*)d_in[0];
    const float* tgt       = (const float*)d_in[1];
    const float* src_feats = (const float*)d_in[2];
    const float* tgt_feats = (const float*)d_in[3];
    const float* src_o     = (const float*)d_in[4];
    const float* tgt_o     = (const float*)d_in[5];
    float* out = (float*)d_out;

    // workspace layout (round-1 proven, NCH=32)
    float* ws = (float*)d_ws;
    size_t off = 0;
    float* Sc    = ws + off; off += (size_t)Bb * Nn * Mm;
    float* Ue    = ws + off; off += Bb * Nn;
    float* Ve    = ws + off; off += Bb * Mm;
    float* logp2 = ws + off; off += Bb * Nn;
    float* logq2 = ws + off; off += Bb * Mm;
    float* nx    = ws + off; off += Bb * Nn;
    float* ny    = ws + off; off += Bb * Mm;
    float* prob  = ws + off; off += Bb * Nn;
    float* corr  = ws + off; off += (size_t)Bb * Nn * 3;
    float* pmx   = ws + off; off += (size_t)Bb * NCH * Mm;
    float* psm   = ws + off; off += (size_t)Bb * NCH * Mm;
    int*   topk  = (int*)(ws + off); off += Bb * TOPK;
    float* bloss = ws + off; off += Bb;
    if (ws_size < off * sizeof(float)) return;

    wl_init_kernel<<<Bb, 256, 0, stream>>>(src_o, tgt_o, logp2, logq2, Ve);
    wl_norms_kernel<<<(Bb * Nn) / 4, 256, 0, stream>>>(src_feats, nx);
    wl_norms_kernel<<<(Bb * Mm) / 4, 256, 0, stream>>>(tgt_feats, ny);
    wl_cost_kernel<<<dim3(Mm / CBN, Nn / CBM, Bb), 256, 0, stream>>>(src_feats, tgt_feats, nx, ny, Sc);

    for (int it = 0; it < SK_ITERS; it++) {
        wl_u_kernel<<<(Bb * Nn) / 4, 256, 0, stream>>>(Sc, Ve, logp2, Ue);
        wl_v_partial_kernel<<<dim3(Mm / 1024, NCH, Bb), 256, 0, stream>>>(Sc, Ue, pmx, psm);
        wl_v_combine_kernel<<<(Bb * Mm) / 256, 256, 0, stream>>>(pmx, psm, logq2, Ve);
    }

    wl_finalize_kernel<<<(Bb * Nn) / 4, 256, 0, stream>>>(Sc, Ue, Ve, tgt, prob, corr);
    wl_topk_kernel<<<Bb, 256, 0, stream>>>(prob, topk);
    wl_edge_kernel<<<Bb, 256, 0, stream>>>(src, corr, topk, bloss);
    wl_final_kernel<<<1, 64, 0, stream>>>(bloss, out);
}